// Round 1
// baseline (851.882 us; speedup 1.0000x reference)
//
#include <hip/hip_runtime.h>
#include <math.h>

#define N   12288
#define D   64
#define CAP 96   // max neighbors/row; Binomial(12288,0.002) mean 24.6, P(>=96) ~ 1e-30

#define CHUNKS      (N * (N / 4))        // 37,748,736 uint4 (16B) chunks of adj
#define SCAN_BLOCKS 2048
#define SCAN_UNROLL 8
#define SCAN_STRIDE (SCAN_BLOCKS * 256)  // 524,288 threads
#define SCAN_PASSES (CHUNKS / (SCAN_STRIDE * SCAN_UNROLL))  // exactly 9, no tail

typedef unsigned int uint4n __attribute__((ext_vector_type(4)));

__device__ __forceinline__ float wave_sum(float v) {
    #pragma unroll
    for (int m = 32; m >= 1; m >>= 1) v += __shfl_xor(v, m, 64);
    return v;
}
__device__ __forceinline__ float sigmoidf(float a) { return 1.0f / (1.0f + __expf(-a)); }

// K1: one wave per row: h = LL(x) kept in registers, then q (negated time) and k
// computed straight from register h. One dispatch for all three linears.
// Also zeroes the per-row neighbor counters for the scan kernel.
__global__ __launch_bounds__(256) void linear_kernel(
        const float* __restrict__ x,
        const float* __restrict__ W,  const float* __restrict__ b,  const float* __restrict__ scale,
        const float* __restrict__ Wq, const float* __restrict__ bq, const float* __restrict__ scale_q,
        const float* __restrict__ Wk, const float* __restrict__ bk, const float* __restrict__ scale_k,
        float* __restrict__ h, float* __restrict__ qm, float* __restrict__ kmat,
        int* __restrict__ cnt) {
    __shared__ float Wl [D * (D + 1)];   // +1 pad: 2-way bank alias (free)
    __shared__ float Wql[D * (D + 1)];
    __shared__ float Wkl[D * (D + 1)];

    const int tid  = threadIdx.x;
    const int lane = tid & 63;
    const int w    = tid >> 6;
    const int row  = blockIdx.x * 4 + w;

    if (tid < 4) cnt[blockIdx.x * 4 + tid] = 0;   // zero counters for scan_kernel

    for (int idx = tid; idx < D * D; idx += 256) {
        int d = idx >> 6, kk = idx & 63;
        Wl [d * (D + 1) + kk] = W [idx];
        Wql[d * (D + 1) + kk] = Wq[idx];
        Wkl[d * (D + 1) + kk] = Wk[idx];
    }
    __syncthreads();

    float hvv;
    {
        float xv  = x[row * D + lane];
        float acc = b[lane];
        const float* wr = &Wl[lane * (D + 1)];
        #pragma unroll
        for (int kk = 0; kk < D; ++kk)
            acc = fmaf(__shfl(xv, kk, 64), wr[kk], acc);
        float h0   = __shfl(acc, 0, 64);
        float time = __expf(scale[0]) * sigmoidf(h0) + 1.1f;
        float sq   = fmaxf(wave_sum((lane == 0) ? 0.0f : acc * acc), 1e-8f);
        float r    = sqrtf((time * time - 1.0f) / sq);
        hvv = (lane == 0) ? time : acc * r;
        h[row * D + lane] = hvv;
    }

    {
        float accq = bq[lane], acck = bk[lane];
        const float* wq = &Wql[lane * (D + 1)];
        const float* wk = &Wkl[lane * (D + 1)];
        #pragma unroll
        for (int kk = 0; kk < D; ++kk) {
            float xk = __shfl(hvv, kk, 64);
            accq = fmaf(xk, wq[kk], accq);
            acck = fmaf(xk, wk[kk], acck);
        }
        {
            float h0   = __shfl(accq, 0, 64);
            float time = __expf(scale_q[0]) * sigmoidf(h0) + 1.1f;
            float sq   = fmaxf(wave_sum((lane == 0) ? 0.0f : accq * accq), 1e-8f);
            float r    = sqrtf((time * time - 1.0f) / sq);
            qm[row * D + lane] = (lane == 0) ? -time : accq * r;
        }
        {
            float h0   = __shfl(acck, 0, 64);
            float time = __expf(scale_k[0]) * sigmoidf(h0) + 1.1f;
            float sq   = fmaxf(wave_sum((lane == 0) ? 0.0f : acck * acck), 1e-8f);
            float r    = sqrtf((time * time - 1.0f) / sq);
            kmat[row * D + lane] = (lane == 0) ? time : acck * r;
        }
    }
}

// K2a: pure-streaming scan of adj (604 MB, read-once, NT so kmat/h stay hot in
// L2/L3). Grid-stride, 8 independent 16B loads in flight per thread, no
// barriers, no per-row serialization. Nonzeros (~0.8% of chunks) take the rare
// path: global atomicAdd into per-row compact neighbor lists.
__global__ __launch_bounds__(256) void scan_kernel(
        const uint4n* __restrict__ adj4,
        int* __restrict__ cnt,
        int* __restrict__ cols) {
    const int idx0 = blockIdx.x * 256 + threadIdx.x;
    for (int p = 0; p < SCAN_PASSES; ++p) {
        const int g0 = idx0 + p * (SCAN_STRIDE * SCAN_UNROLL);
        uint4n v[SCAN_UNROLL];
        #pragma unroll
        for (int k = 0; k < SCAN_UNROLL; ++k)
            v[k] = __builtin_nontemporal_load(&adj4[g0 + k * SCAN_STRIDE]);
        #pragma unroll
        for (int k = 0; k < SCAN_UNROLL; ++k) {
            uint4n vk = v[k];
            if ((vk.x | vk.y | vk.z | vk.w) != 0u) {
                int g   = g0 + k * SCAN_STRIDE;
                int row = g / (N / 4);                 // rare path; magic-mul div
                int cb  = (g - row * (N / 4)) * 4;
                unsigned e[4] = {vk.x, vk.y, vk.z, vk.w};
                #pragma unroll
                for (int c = 0; c < 4; ++c) {
                    if (e[c] != 0u) {
                        int pos = atomicAdd(&cnt[row], 1);
                        if (pos < CAP) cols[row * CAP + pos] = cb + c;
                    }
                }
            }
        }
    }
}

// K2b: per-row gather from the compact lists. kmat/h (3 MB each) are L2/L3
// resident; 4 waves split the ~25 neighbors, LDS combine, Lorentz normalize.
__global__ __launch_bounds__(256) void gather_kernel(
        const int* __restrict__ cnt,
        const int* __restrict__ cols,
        const float* __restrict__ qm,
        const float* __restrict__ kmat,
        const float* __restrict__ h,
        const float* __restrict__ att_bias_p,
        const float* __restrict__ att_scale_p,
        float* __restrict__ out) {
    __shared__ float sacc[4][D];

    const int tid  = threadIdx.x;
    const int row  = blockIdx.x;
    const int lane = tid & 63;
    const int w    = tid >> 6;

    float qv        = qm[row * D + lane];
    float bias      = att_bias_p[0];
    float inv_scale = 1.0f / att_scale_p[0];

    int m = cnt[row]; if (m > CAP) m = CAP;
    const int* cl = cols + row * CAP;

    float acc = 0.0f;
    int n = w;
    int j = (n < m) ? cl[n] : 0;
    for (; n < m; n += 4) {
        int jn = (n + 4 < m) ? cl[n + 4] : 0;      // prefetch next list entry
        float kv = kmat[j * D + lane];
        float hv = h[j * D + lane];
        float dot = wave_sum(qv * kv);
        float att = sigmoidf(fmaf(2.0f + 2.0f * dot, inv_scale, bias));
        acc = fmaf(att, hv, acc);
        j = jn;
    }
    sacc[w][lane] = acc;
    __syncthreads();

    if (w == 0) {
        float total   = sacc[0][lane] + sacc[1][lane] + sacc[2][lane] + sacc[3][lane];
        float contrib = (lane == 0) ? -total * total : total * total;
        float inner   = wave_sum(contrib);
        float denorm  = sqrtf(fmaxf(fabsf(inner), 1e-8f));
        out[row * D + lane] = total / denorm;
    }
}

extern "C" void kernel_launch(void* const* d_in, const int* in_sizes, int n_in,
                              void* d_out, int out_size, void* d_ws, size_t ws_size,
                              hipStream_t stream) {
    const float*  x         = (const float*)d_in[0];
    const uint4n* adj       = (const uint4n*)d_in[1];
    const float*  W         = (const float*)d_in[2];
    const float*  b         = (const float*)d_in[3];
    const float*  scale     = (const float*)d_in[4];
    const float*  Wq        = (const float*)d_in[5];
    const float*  bq        = (const float*)d_in[6];
    const float*  scale_q   = (const float*)d_in[7];
    const float*  Wk        = (const float*)d_in[8];
    const float*  bk        = (const float*)d_in[9];
    const float*  scale_k   = (const float*)d_in[10];
    const float*  att_bias  = (const float*)d_in[11];
    const float*  att_scale = (const float*)d_in[12];
    float* out = (float*)d_out;

    float* h    = (float*)d_ws;                 // N*D f32
    float* qm   = h    + (size_t)N * D;         // N*D f32
    float* kmat = qm   + (size_t)N * D;         // N*D f32
    int*   cnt  = (int*)(kmat + (size_t)N * D); // N i32
    int*   cols = cnt  + N;                     // N*CAP i32  (total ws ~14.2 MB)

    linear_kernel<<<N / 4, 256, 0, stream>>>(x, W, b, scale,
                                             Wq, bq, scale_q, Wk, bk, scale_k,
                                             h, qm, kmat, cnt);
    scan_kernel<<<SCAN_BLOCKS, 256, 0, stream>>>(adj, cnt, cols);
    gather_kernel<<<N, 256, 0, stream>>>(cnt, cols, qm, kmat, h,
                                         att_bias, att_scale, out);
}